// Round 5
// baseline (330.160 us; speedup 1.0000x reference)
//
#include <hip/hip_runtime.h>
#include <hip/hip_bf16.h>
#include <stdint.h>

// B=8, L=4096, T=512, D_H=1280, D_G=768, D_P=256, scale = 1/16

typedef float f32x4 __attribute__((ext_vector_type(4)));
typedef short bf16x8 __attribute__((ext_vector_type(8)));

__device__ __forceinline__ unsigned short f2bf(float f) {
    __hip_bfloat16 h = __float2bfloat16(f);
    return __builtin_bit_cast(unsigned short, h);
}
__device__ __forceinline__ float bf2f(unsigned short h) {
    union { uint32_t u; float f; } v; v.u = ((uint32_t)h) << 16;
    return v.f;
}

// bijective XCD-chunk swizzle (gridDim.x % 8 == 0 at all call sites)
__device__ __forceinline__ int xcdswz(int bx, int nbx) {
    int cpx = nbx >> 3;
    return (bx & 7) * cpx + (bx >> 3);
}

// async global->LDS, 16B per lane; LDS dest = wave-uniform base + lane*16
__device__ __forceinline__ void gload16(const unsigned short* g, unsigned short* l) {
    __builtin_amdgcn_global_load_lds(
        (const __attribute__((address_space(1))) void*)g,
        (__attribute__((address_space(3))) void*)l,
        16, 0, 0);
}

// legacy LDS index for f32-staged projection GEMM
__device__ __forceinline__ int lidx(int row, int kshort) {
    return row * 40 + (((kshort >> 3) ^ ((row >> 3) & 3)) << 3) + (kshort & 7);
}

// ---------------------------------------------------------------------------
// Projection GEMM (f32 inputs, cvt in staging). Tile 128x128, BK=32.
// ---------------------------------------------------------------------------
template<bool TNF>
__global__ __launch_bounds__(256)
void gemm_bt(const float* __restrict__ Ap, const float* __restrict__ Bp,
             unsigned short* __restrict__ Cp, int M, int N, int K)
{
    __shared__ __align__(16) unsigned short lA[128 * 40];
    __shared__ __align__(16) unsigned short lB[128 * 40];

    const int bx = xcdswz(blockIdx.x, gridDim.x);
    const int mt = M >> 7, nt = N >> 7;
    const int tm = TNF ? (bx / nt) : (bx % mt);
    const int tn = TNF ? (bx % nt) : (bx / mt);
    const int tid = threadIdx.x;
    const int lane = tid & 63, wv = tid >> 6;
    const int wr = wv >> 1, wc = wv & 1;
    const int fr = lane & 15, fk = lane >> 4;

    f32x4 acc[4][4] = {};

    for (int k0 = 0; k0 < K; k0 += 32) {
        {
            const float* A = Ap + (long)tm * 128 * K + k0;
            #pragma unroll
            for (int it = 0; it < 4; ++it) {
                int chunk = it * 256 + tid;
                int row = chunk >> 3;
                int kc  = (chunk & 7) << 2;
                const float4 v = *(const float4*)(A + (long)row * K + kc);
                ushort4 w;
                w.x = f2bf(v.x); w.y = f2bf(v.y); w.z = f2bf(v.z); w.w = f2bf(v.w);
                *(ushort4*)(&lA[lidx(row, kc)]) = w;
            }
        }
        {
            const float* B = Bp + (long)tn * 128 * K + k0;
            #pragma unroll
            for (int it = 0; it < 4; ++it) {
                int chunk = it * 256 + tid;
                int row = chunk >> 3;
                int kc  = (chunk & 7) << 2;
                const float4 v = *(const float4*)(B + (long)row * K + kc);
                ushort4 w;
                w.x = f2bf(v.x); w.y = f2bf(v.y); w.z = f2bf(v.z); w.w = f2bf(v.w);
                *(ushort4*)(&lB[lidx(row, kc)]) = w;
            }
        }
        __syncthreads();
        bf16x8 af[4], bfr[4];
        #pragma unroll
        for (int i = 0; i < 4; ++i)
            af[i] = *(const bf16x8*)(&lA[lidx(wr * 64 + i * 16 + fr, fk * 8)]);
        #pragma unroll
        for (int i = 0; i < 4; ++i)
            bfr[i] = *(const bf16x8*)(&lB[lidx(wc * 64 + i * 16 + fr, fk * 8)]);
        #pragma unroll
        for (int mi = 0; mi < 4; ++mi)
            #pragma unroll
            for (int ni = 0; ni < 4; ++ni)
                acc[mi][ni] = __builtin_amdgcn_mfma_f32_16x16x32_bf16(af[mi], bfr[ni], acc[mi][ni], 0, 0, 0);
        __syncthreads();
    }

    unsigned short* C = Cp + ((long)tm * 128) * N + (long)tn * 128;
    #pragma unroll
    for (int mi = 0; mi < 4; ++mi)
        #pragma unroll
        for (int ni = 0; ni < 4; ++ni)
            #pragma unroll
            for (int j = 0; j < 4; ++j) {
                int m = wr * 64 + mi * 16 + fk * 4 + j;
                int n = wc * 64 + ni * 16 + fr;
                C[(long)m * N + n] = f2bf(acc[mi][ni][j]);
            }
}

// ---------------------------------------------------------------------------
// All-bf16 C = scale*A@B^T. Tile 128x128, BK=64, 4 waves 2x2 (wave 64x64).
// gload16 staging with pre-swizzled source; XOR-swizzled reads.
// ---------------------------------------------------------------------------
__global__ __launch_bounds__(256)
void gemm_bt16s(const unsigned short* __restrict__ Ap, const unsigned short* __restrict__ Bp,
                unsigned short* __restrict__ Cp, int M, int N, int K,
                long sA, long sB, long sC, float scale)
{
    __shared__ __align__(16) unsigned short lA[128 * 64];   // 16KB
    __shared__ __align__(16) unsigned short lB[128 * 64];   // 16KB

    const int bx = xcdswz(blockIdx.x, gridDim.x);
    const int mt = M >> 7;
    const int tm = bx % mt, tn = bx / mt;
    const int b  = blockIdx.y;
    const int tid = threadIdx.x;
    const int lane = tid & 63, wv = tid >> 6;
    const int wr = wv >> 1, wc = wv & 1;
    const int fr = lane & 15, fk = lane >> 4;

    f32x4 acc[4][4] = {};

    const unsigned short* A0 = Ap + (long)b * sA + (long)tm * 128 * K;
    const unsigned short* B0 = Bp + (long)b * sB + (long)tn * 128 * K;

    for (int k0 = 0; k0 < K; k0 += 64) {
        // 128 rows x 8 chunks(16B) = 1024 slots per tile; 4 issues/thread each
        #pragma unroll
        for (int q = 0; q < 4; ++q) {
            int slot = wv * 256 + q * 64 + lane;
            int row = slot >> 3, c = slot & 7;
            int ks = (c ^ (row & 7)) << 3;                 // pre-swizzled source chunk
            gload16(A0 + (long)row * K + k0 + ks, lA + (size_t)(wv * 256 + q * 64) * 8);
            gload16(B0 + (long)row * K + k0 + ks, lB + (size_t)(wv * 256 + q * 64) * 8);
        }
        __syncthreads();
        bf16x8 af[2][4], bfv[2][4];
        #pragma unroll
        for (int ks = 0; ks < 2; ++ks) {
            int csw = ((ks * 4 + fk) ^ (fr & 7)) << 3;
            #pragma unroll
            for (int i = 0; i < 4; ++i) {
                af[ks][i]  = *(const bf16x8*)(lA + (wr * 64 + i * 16 + fr) * 64 + csw);
                bfv[ks][i] = *(const bf16x8*)(lB + (wc * 64 + i * 16 + fr) * 64 + csw);
            }
        }
        #pragma unroll
        for (int mi = 0; mi < 4; ++mi)
            #pragma unroll
            for (int ni = 0; ni < 4; ++ni)
                #pragma unroll
                for (int ks = 0; ks < 2; ++ks)
                    acc[mi][ni] = __builtin_amdgcn_mfma_f32_16x16x32_bf16(af[ks][mi], bfv[ks][ni], acc[mi][ni], 0, 0, 0);
        __syncthreads();
    }

    unsigned short* C = Cp + (long)b * sC + ((long)tm * 128) * N + (long)tn * 128;
    #pragma unroll
    for (int mi = 0; mi < 4; ++mi)
        #pragma unroll
        for (int ni = 0; ni < 4; ++ni)
            #pragma unroll
            for (int j = 0; j < 4; ++j) {
                int m = wr * 64 + mi * 16 + fk * 4 + j;
                int n = wc * 64 + ni * 16 + fr;
                C[(long)m * N + n] = f2bf(acc[mi][ni][j] * scale);
            }
}

// ---------------------------------------------------------------------------
// Z = alpha @ Hbt^T. Per batch M=512,N=1280,K=4096. Tile 128x64, 4 waves,
// EACH wave computes the full tile over a 32-wide k-slice (BK_block=128);
// deterministic sequential k-reduction through LDS (f32x4) in the epilogue.
// K-tile = 128 elems = 16 chunks of 16B per row.
// ---------------------------------------------------------------------------
__global__ __launch_bounds__(256)
void zk(const unsigned short* __restrict__ Sb, const unsigned short* __restrict__ Hbt,
        float* __restrict__ out)
{
    __shared__ __align__(16) unsigned short lA[128 * 128];  // 32KB (alpha tile)
    __shared__ __align__(16) unsigned short lB[64 * 128];   // 16KB (Hbt tile)

    const int K = 4096, N = 1280;
    const int bx = xcdswz(blockIdx.x, gridDim.x);           // 80 blocks/batch
    const int tm = bx & 3, tn = bx >> 2;                    // tn 0..19
    const int b  = blockIdx.y;
    const int tid = threadIdx.x;
    const int lane = tid & 63, wv = tid >> 6;
    const int fr = lane & 15, fk = lane >> 4;

    f32x4 acc[8][4] = {};

    const unsigned short* A0 = Sb  + ((long)b * 512  + tm * 128) * K;
    const unsigned short* B0 = Hbt + ((long)b * 1280 + tn * 64) * K;

    for (int k0 = 0; k0 < K; k0 += 128) {
        // A: 128 rows x 16 chunks = 2048 slots -> 8 issues/thread
        #pragma unroll
        for (int q = 0; q < 8; ++q) {
            int slot = wv * 512 + q * 64 + lane;
            int row = slot >> 4, c = slot & 15;
            gload16(A0 + (long)row * K + k0 + ((c ^ (row & 7)) << 3),
                    lA + (size_t)(wv * 512 + q * 64) * 8);
        }
        // B: 64 rows x 16 chunks = 1024 slots -> 4 issues/thread
        #pragma unroll
        for (int q = 0; q < 4; ++q) {
            int slot = wv * 256 + q * 64 + lane;
            int row = slot >> 4, c = slot & 15;
            gload16(B0 + (long)row * K + k0 + ((c ^ (row & 7)) << 3),
                    lB + (size_t)(wv * 256 + q * 64) * 8);
        }
        __syncthreads();
        const int csw = ((wv * 4 + fk) ^ (fr & 7)) << 3;    // wave's k-slice chunk, swizzled
        bf16x8 bfv[4];
        #pragma unroll
        for (int i = 0; i < 4; ++i)
            bfv[i] = *(const bf16x8*)(lB + (i * 16 + fr) * 128 + csw);
        #pragma unroll
        for (int mi = 0; mi < 8; ++mi) {
            bf16x8 af = *(const bf16x8*)(lA + (mi * 16 + fr) * 128 + csw);
            #pragma unroll
            for (int ni = 0; ni < 4; ++ni)
                acc[mi][ni] = __builtin_amdgcn_mfma_f32_16x16x32_bf16(af, bfv[ni], acc[mi][ni], 0, 0, 0);
        }
        __syncthreads();
    }

    // deterministic k-split reduction: waves 1..3 hand acc to wave 0 via LDS
    // (f32x4 slots: (mi*4+ni)*64 + lane -> 2048 slots = 32KB, fits in lA)
    f32x4* red = (f32x4*)lA;
    #pragma unroll 1
    for (int w = 1; w < 4; ++w) {
        __syncthreads();
        if (wv == w) {
            #pragma unroll
            for (int mi = 0; mi < 8; ++mi)
                #pragma unroll
                for (int ni = 0; ni < 4; ++ni)
                    red[(mi * 4 + ni) * 64 + lane] = acc[mi][ni];
        }
        __syncthreads();
        if (wv == 0) {
            #pragma unroll
            for (int mi = 0; mi < 8; ++mi)
                #pragma unroll
                for (int ni = 0; ni < 4; ++ni) {
                    f32x4 v = red[(mi * 4 + ni) * 64 + lane];
                    acc[mi][ni][0] += v[0]; acc[mi][ni][1] += v[1];
                    acc[mi][ni][2] += v[2]; acc[mi][ni][3] += v[3];
                }
        }
    }
    if (wv == 0) {
        float* C = out + ((long)b * 512 + tm * 128) * N + tn * 64;
        #pragma unroll
        for (int mi = 0; mi < 8; ++mi)
            #pragma unroll
            for (int ni = 0; ni < 4; ++ni)
                #pragma unroll
                for (int j = 0; j < 4; ++j)
                    C[(long)(mi * 16 + fk * 4 + j) * N + ni * 16 + fr] = acc[mi][ni][j];
    }
}

// ---------------------------------------------------------------------------
// H [8][4096][1280] f32 -> Hbt [8][1280][4096] bf16 (transpose + convert)
// ---------------------------------------------------------------------------
__global__ __launch_bounds__(256)
void transpose_h(const float* __restrict__ H, unsigned short* __restrict__ Hbt)
{
    __shared__ unsigned short lT[64 * 72];
    const int ntile = 64 * 20 * 8;
    for (int tileid = blockIdx.x; tileid < ntile; tileid += gridDim.x) {
        int tmp = tileid;
        const int dt = tmp % 20; tmp /= 20;
        const int lt = tmp % 64;
        const int b  = tmp / 64;
        const int l0 = lt * 64, d0 = dt * 64;
        const float* Hs = H + ((long)b * 4096 + l0) * 1280 + d0;
        #pragma unroll
        for (int it = 0; it < 4; ++it) {
            int chunk = it * 256 + threadIdx.x;
            int lr = chunk >> 4, dc4 = (chunk & 15) << 2;
            float4 v = *(const float4*)(Hs + (long)lr * 1280 + dc4);
            unsigned short w[4] = { f2bf(v.x), f2bf(v.y), f2bf(v.z), f2bf(v.w) };
            #pragma unroll
            for (int j = 0; j < 4; ++j) {
                int d = dc4 + j;
                int sl = (lr & 15) | ((((lr >> 4) ^ (d >> 2)) & 3) << 4);
                lT[d * 72 + sl] = w[j];
            }
        }
        __syncthreads();
        {
            int drow = threadIdx.x >> 2, lc = threadIdx.x & 3;
            int slc = lc ^ ((drow >> 2) & 3);
            const uint4* src = (const uint4*)(lT + drow * 72 + slc * 16);
            unsigned short* dst = Hbt + ((long)b * 1280 + d0 + drow) * 4096 + l0 + lc * 16;
            uint4 v0 = src[0], v1 = src[1];
            *(uint4*)(dst)     = v0;
            *(uint4*)(dst + 8) = v1;
        }
        __syncthreads();
    }
}

// ---------------------------------------------------------------------------
// Fallback Z-GEMM (small-ws path)
// ---------------------------------------------------------------------------
__global__ __launch_bounds__(256)
void gemm_kn(const unsigned short* __restrict__ Ap, const float* __restrict__ Bp,
             float* __restrict__ Cp, int M, int N, int K,
             long sA, long sB, long sC)
{
    __shared__ __align__(16) unsigned short lA[128 * 40];
    __shared__ __align__(16) unsigned short lB[64 * 40];

    const int bx = xcdswz(blockIdx.x, gridDim.x);
    const int mt = M >> 7;
    const int tm = bx % mt;
    const int tn = bx / mt;
    const int b  = blockIdx.y;
    const int tid = threadIdx.x;
    const int lane = tid & 63, wv = tid >> 6;
    const int wr = wv >> 1, wc = wv & 1;
    const int fr = lane & 15, fk = lane >> 4;

    f32x4 acc[4][2] = {};

    const unsigned short* A0 = Ap + (long)b * sA + (long)tm * 128 * K;
    const int nn    = tid & 63;
    const int khalf = tid >> 6;

    for (int k0 = 0; k0 < K; k0 += 32) {
        #pragma unroll
        for (int it = 0; it < 2; ++it) {
            int chunk = it * 256 + tid;
            int row = chunk >> 2;
            int kc  = (chunk & 3) << 3;
            *(uint4*)(&lA[lidx(row, kc)]) = *(const uint4*)(A0 + (long)row * K + k0 + kc);
        }
        {
            const float* Bb = Bp + (long)b * sB + (long)(k0 + khalf * 8) * N + (long)tn * 64 + nn;
            unsigned short t8[8];
            #pragma unroll
            for (int kk = 0; kk < 8; ++kk)
                t8[kk] = f2bf(Bb[(long)kk * N]);
            *(uint4*)(&lB[lidx(nn, khalf * 8)]) = *(uint4*)(&t8[0]);
        }
        __syncthreads();
        bf16x8 af[4], bfr[2];
        #pragma unroll
        for (int i = 0; i < 4; ++i)
            af[i] = *(const bf16x8*)(&lA[lidx(wr * 64 + i * 16 + fr, fk * 8)]);
        #pragma unroll
        for (int i = 0; i < 2; ++i)
            bfr[i] = *(const bf16x8*)(&lB[lidx(wc * 32 + i * 16 + fr, fk * 8)]);
        #pragma unroll
        for (int mi = 0; mi < 4; ++mi)
            #pragma unroll
            for (int ni = 0; ni < 2; ++ni)
                acc[mi][ni] = __builtin_amdgcn_mfma_f32_16x16x32_bf16(af[mi], bfr[ni], acc[mi][ni], 0, 0, 0);
        __syncthreads();
    }

    float* C = Cp + (long)b * sC + ((long)tm * 128) * N + (long)tn * 64;
    #pragma unroll
    for (int mi = 0; mi < 4; ++mi)
        #pragma unroll
        for (int ni = 0; ni < 2; ++ni)
            #pragma unroll
            for (int j = 0; j < 4; ++j) {
                int m = wr * 64 + mi * 16 + fk * 4 + j;
                int n = wc * 32 + ni * 16 + fr;
                C[(long)m * N + n] = acc[mi][ni][j];
            }
}

// ---------------------------------------------------------------------------
// Row softmax in place on S (bf16), rows of length 4096.
// ---------------------------------------------------------------------------
__global__ __launch_bounds__(256)
void softmax_rows(unsigned short* __restrict__ S, const unsigned char* __restrict__ mask)
{
    const int row = blockIdx.x;
    const int b = row >> 9;
    const long base = (long)row * 4096;
    const int tid = threadIdx.x, lane = tid & 63, wv = tid >> 6;
    __shared__ float red[8];

    uint4 s0 = *(const uint4*)(S + base + tid * 16);
    uint4 s1 = *(const uint4*)(S + base + tid * 16 + 8);
    uint4 mv = *(const uint4*)(mask + (long)b * 4096 + tid * 16);
    const unsigned char* mb = (const unsigned char*)&mv;

    unsigned int words[8] = { s0.x, s0.y, s0.z, s0.w, s1.x, s1.y, s1.z, s1.w };
    float x[16];
    #pragma unroll
    for (int i = 0; i < 8; ++i) {
        x[2 * i]     = bf2f((unsigned short)(words[i] & 0xffffu));
        x[2 * i + 1] = bf2f((unsigned short)(words[i] >> 16));
    }
    #pragma unroll
    for (int i = 0; i < 16; ++i)
        if (mb[i]) x[i] = -1e30f;

    float m = x[0];
    #pragma unroll
    for (int i = 1; i < 16; ++i) m = fmaxf(m, x[i]);
    #pragma unroll
    for (int off = 32; off; off >>= 1) m = fmaxf(m, __shfl_xor(m, off));
    if (lane == 0) red[wv] = m;
    __syncthreads();
    m = fmaxf(fmaxf(red[0], red[1]), fmaxf(red[2], red[3]));

    float p[16];
    float s = 0.f;
    #pragma unroll
    for (int i = 0; i < 16; ++i) { p[i] = __expf(x[i] - m); s += p[i]; }
    #pragma unroll
    for (int off = 32; off; off >>= 1) s += __shfl_xor(s, off);
    if (lane == 0) red[4 + wv] = s;
    __syncthreads();
    s = (red[4] + red[5]) + (red[6] + red[7]);
    const float inv = 1.0f / s;

    unsigned int ow[8];
    #pragma unroll
    for (int i = 0; i < 8; ++i) {
        unsigned int lo = f2bf(p[2 * i] * inv);
        unsigned int hi = f2bf(p[2 * i + 1] * inv);
        ow[i] = lo | (hi << 16);
    }
    uint4 o0 = { ow[0], ow[1], ow[2], ow[3] };
    uint4 o1 = { ow[4], ow[5], ow[6], ow[7] };
    *(uint4*)(S + base + tid * 16)     = o0;
    *(uint4*)(S + base + tid * 16 + 8) = o1;
}

// ---------------------------------------------------------------------------
extern "C" void kernel_launch(void* const* d_in, const int* in_sizes, int n_in,
                              void* d_out, int out_size, void* d_ws, size_t ws_size,
                              hipStream_t stream)
{
    const float*         H    = (const float*)d_in[0];
    const float*         G    = (const float*)d_in[1];
    const unsigned char* mask = (const unsigned char*)d_in[2];
    const float*         Wk   = (const float*)d_in[3];
    const float*         Wq   = (const float*)d_in[4];
    float*               out  = (float*)d_out;

    const long nK = (long)8 * 4096 * 256;
    const long nQ = (long)8 * 512 * 256;
    const long nS = (long)8 * 512 * 4096;
    const long nH = (long)8 * 1280 * 4096;

    unsigned short* Kb  = (unsigned short*)d_ws;
    unsigned short* Qb  = Kb + nK;
    unsigned short* Sb  = Qb + nQ;
    unsigned short* Hbt = Sb + nS;
    const bool big = ws_size >= (size_t)(nK + nQ + nS + nH) * 2;

    // 1) K = H @ Wk^T  (M=32768,N=256,K=1280)
    gemm_bt<true><<<dim3(512, 1), 256, 0, stream>>>(H, Wk, Kb, 32768, 256, 1280);
    // 2) Q = G @ Wq^T  (M=4096,N=256,K=768)
    gemm_bt<true><<<dim3(64, 1), 256, 0, stream>>>(G, Wq, Qb, 4096, 256, 768);

    if (big) {
        // 3) Hbt = transpose(H) bf16
        transpose_h<<<dim3(2048), 256, 0, stream>>>(H, Hbt);
        // 4) S = Q @ K^T * scale  per batch (M=512,N=4096,K=256)
        gemm_bt16s<<<dim3(128, 8), 256, 0, stream>>>(
            Qb, Kb, Sb, 512, 4096, 256,
            (long)512 * 256, (long)4096 * 256, (long)512 * 4096, 0.0625f);
        // 5) softmax
        softmax_rows<<<dim3(4096), 256, 0, stream>>>(Sb, mask);
        // 6) Z = alpha @ Hbt^T  per batch (M=512,N=1280,K=4096)
        zk<<<dim3(80, 8), 256, 0, stream>>>(Sb, Hbt, out);
    } else {
        gemm_bt16s<<<dim3(128, 8), 256, 0, stream>>>(
            Qb, Kb, Sb, 512, 4096, 256,
            (long)512 * 256, (long)4096 * 256, (long)512 * 4096, 0.0625f);
        softmax_rows<<<dim3(4096), 256, 0, stream>>>(Sb, mask);
        gemm_kn<<<dim3(80, 8), 256, 0, stream>>>(
            Sb, H, out, 512, 1280, 4096,
            (long)512 * 4096, (long)4096 * 1280, (long)512 * 1280);
    }
}

// Round 6
// 282.306 us; speedup vs baseline: 1.1695x; 1.1695x over previous
//
#include <hip/hip_runtime.h>
#include <hip/hip_bf16.h>
#include <stdint.h>

// B=8, L=4096, T=512, D_H=1280, D_G=768, D_P=256, scale = 1/16

typedef float f32x4 __attribute__((ext_vector_type(4)));
typedef short bf16x8 __attribute__((ext_vector_type(8)));

__device__ __forceinline__ unsigned short f2bf(float f) {
    __hip_bfloat16 h = __float2bfloat16(f);
    return __builtin_bit_cast(unsigned short, h);
}
__device__ __forceinline__ float bf2f(unsigned short h) {
    union { uint32_t u; float f; } v; v.u = ((uint32_t)h) << 16;
    return v.f;
}

// bijective XCD-chunk swizzle (gridDim.x % 8 == 0 at all call sites)
__device__ __forceinline__ int xcdswz(int bx, int nbx) {
    int cpx = nbx >> 3;
    return (bx & 7) * cpx + (bx >> 3);
}

// async global->LDS, 16B per lane; LDS dest = wave-uniform base + lane*16
__device__ __forceinline__ void gload16(const unsigned short* g, unsigned short* l) {
    __builtin_amdgcn_global_load_lds(
        (const __attribute__((address_space(1))) void*)g,
        (__attribute__((address_space(3))) void*)l,
        16, 0, 0);
}

// LDS index for f32-staged kernels (padded stride 40 + granule XOR swizzle)
__device__ __forceinline__ int lidx(int row, int kshort) {
    return row * 40 + (((kshort >> 3) ^ ((row >> 3) & 3)) << 3) + (kshort & 7);
}

// ---------------------------------------------------------------------------
// Projection GEMM: C[m,n] = sum_k A[m,k]*B[n,k], f32 inputs (cvt in staging),
// bf16 out. Tile 128x128, BK=32, 4 waves 2x2. TNF mapping (tn fastest).
// WRITE_HBT: tn==0 blocks also emit the A tile TRANSPOSED to Hbt
// [8][1280][4096] bf16 (fused transpose; H read exactly once by the pipeline).
// ---------------------------------------------------------------------------
template<bool WRITE_HBT>
__global__ __launch_bounds__(256)
void gemm_proj(const float* __restrict__ Ap, const float* __restrict__ Bp,
               unsigned short* __restrict__ Cp, int M, int N, int K,
               unsigned short* __restrict__ Hbt)
{
    __shared__ __align__(16) unsigned short lA[128 * 40];
    __shared__ __align__(16) unsigned short lB[128 * 40];

    const int bx = xcdswz(blockIdx.x, gridDim.x);
    const int nt = N >> 7;
    const int tm = bx / nt;
    const int tn = bx % nt;
    const int tid = threadIdx.x;
    const int lane = tid & 63, wv = tid >> 6;
    const int wr = wv >> 1, wc = wv & 1;
    const int fr = lane & 15, fk = lane >> 4;

    f32x4 acc[4][4] = {};

    for (int k0 = 0; k0 < K; k0 += 32) {
        {
            const float* A = Ap + (long)tm * 128 * K + k0;
            #pragma unroll
            for (int it = 0; it < 4; ++it) {
                int chunk = it * 256 + tid;
                int row = chunk >> 3;
                int kc  = (chunk & 7) << 2;
                const float4 v = *(const float4*)(A + (long)row * K + kc);
                ushort4 w;
                w.x = f2bf(v.x); w.y = f2bf(v.y); w.z = f2bf(v.z); w.w = f2bf(v.w);
                *(ushort4*)(&lA[lidx(row, kc)]) = w;
                if constexpr (WRITE_HBT) {
                    if (tn == 0) {
                        int gm = tm * 128 + row;          // global row in [0,32768)
                        int bb = gm >> 12, ll = gm & 4095;
                        unsigned short wa[4] = { w.x, w.y, w.z, w.w };
                        #pragma unroll
                        for (int j = 0; j < 4; ++j)
                            Hbt[((long)bb * 1280 + k0 + kc + j) * 4096 + ll] = wa[j];
                    }
                }
            }
        }
        {
            const float* B = Bp + (long)tn * 128 * K + k0;
            #pragma unroll
            for (int it = 0; it < 4; ++it) {
                int chunk = it * 256 + tid;
                int row = chunk >> 3;
                int kc  = (chunk & 7) << 2;
                const float4 v = *(const float4*)(B + (long)row * K + kc);
                ushort4 w;
                w.x = f2bf(v.x); w.y = f2bf(v.y); w.z = f2bf(v.z); w.w = f2bf(v.w);
                *(ushort4*)(&lB[lidx(row, kc)]) = w;
            }
        }
        __syncthreads();
        bf16x8 af[4], bfr[4];
        #pragma unroll
        for (int i = 0; i < 4; ++i)
            af[i] = *(const bf16x8*)(&lA[lidx(wr * 64 + i * 16 + fr, fk * 8)]);
        #pragma unroll
        for (int i = 0; i < 4; ++i)
            bfr[i] = *(const bf16x8*)(&lB[lidx(wc * 64 + i * 16 + fr, fk * 8)]);
        #pragma unroll
        for (int mi = 0; mi < 4; ++mi)
            #pragma unroll
            for (int ni = 0; ni < 4; ++ni)
                acc[mi][ni] = __builtin_amdgcn_mfma_f32_16x16x32_bf16(af[mi], bfr[ni], acc[mi][ni], 0, 0, 0);
        __syncthreads();
    }

    unsigned short* C = Cp + ((long)tm * 128) * N + (long)tn * 128;
    #pragma unroll
    for (int mi = 0; mi < 4; ++mi)
        #pragma unroll
        for (int ni = 0; ni < 4; ++ni)
            #pragma unroll
            for (int j = 0; j < 4; ++j) {
                int m = wr * 64 + mi * 16 + fk * 4 + j;
                int n = wc * 64 + ni * 16 + fr;
                C[(long)m * N + n] = f2bf(acc[mi][ni][j]);
            }
}

// ---------------------------------------------------------------------------
// All-bf16 C = scale*A@B^T (m97 structure). Tile 128x128, BK=64, 4 waves 2x2
// (wave 64x64). gload16 staging, pre-swizzled source + XOR-swizzled reads.
// OF32: f32 output (for Z), else bf16.
// ---------------------------------------------------------------------------
template<bool OF32>
__global__ __launch_bounds__(256)
void gemm_bt16s(const unsigned short* __restrict__ Ap, const unsigned short* __restrict__ Bp,
                void* __restrict__ Cp, int M, int N, int K,
                long sA, long sB, long sC, float scale)
{
    __shared__ __align__(16) unsigned short lA[128 * 64];   // 16KB
    __shared__ __align__(16) unsigned short lB[128 * 64];   // 16KB

    const int bx = xcdswz(blockIdx.x, gridDim.x);
    const int nt = N >> 7;
    const int tm = bx / nt, tn = bx % nt;   // tn fastest (A-strip sharers adjacent)
    const int b  = blockIdx.y;
    const int tid = threadIdx.x;
    const int lane = tid & 63, wv = tid >> 6;
    const int wr = wv >> 1, wc = wv & 1;
    const int fr = lane & 15, fk = lane >> 4;

    f32x4 acc[4][4] = {};

    const unsigned short* A0 = Ap + (long)b * sA + (long)tm * 128 * K;
    const unsigned short* B0 = Bp + (long)b * sB + (long)tn * 128 * K;

    for (int k0 = 0; k0 < K; k0 += 64) {
        // 128 rows x 8 chunks(16B) = 1024 slots per tile; 4 issues/thread each
        #pragma unroll
        for (int q = 0; q < 4; ++q) {
            int slot = wv * 256 + q * 64 + lane;
            int row = slot >> 3, c = slot & 7;
            int ks = (c ^ (row & 7)) << 3;                 // pre-swizzled source chunk
            gload16(A0 + (long)row * K + k0 + ks, lA + (size_t)(wv * 256 + q * 64) * 8);
            gload16(B0 + (long)row * K + k0 + ks, lB + (size_t)(wv * 256 + q * 64) * 8);
        }
        __syncthreads();
        bf16x8 af[2][4], bfv[2][4];
        #pragma unroll
        for (int ks = 0; ks < 2; ++ks) {
            int csw = ((ks * 4 + fk) ^ (fr & 7)) << 3;
            #pragma unroll
            for (int i = 0; i < 4; ++i) {
                af[ks][i]  = *(const bf16x8*)(lA + (wr * 64 + i * 16 + fr) * 64 + csw);
                bfv[ks][i] = *(const bf16x8*)(lB + (wc * 64 + i * 16 + fr) * 64 + csw);
            }
        }
        #pragma unroll
        for (int mi = 0; mi < 4; ++mi)
            #pragma unroll
            for (int ni = 0; ni < 4; ++ni)
                #pragma unroll
                for (int ks = 0; ks < 2; ++ks)
                    acc[mi][ni] = __builtin_amdgcn_mfma_f32_16x16x32_bf16(af[ks][mi], bfv[ks][ni], acc[mi][ni], 0, 0, 0);
        __syncthreads();
    }

    if constexpr (OF32) {
        float* C = (float*)Cp + (long)b * sC + ((long)tm * 128) * N + (long)tn * 128;
        #pragma unroll
        for (int mi = 0; mi < 4; ++mi)
            #pragma unroll
            for (int ni = 0; ni < 4; ++ni)
                #pragma unroll
                for (int j = 0; j < 4; ++j) {
                    int m = wr * 64 + mi * 16 + fk * 4 + j;
                    int n = wc * 64 + ni * 16 + fr;
                    C[(long)m * N + n] = acc[mi][ni][j] * scale;
                }
    } else {
        unsigned short* C = (unsigned short*)Cp + (long)b * sC + ((long)tm * 128) * N + (long)tn * 128;
        #pragma unroll
        for (int mi = 0; mi < 4; ++mi)
            #pragma unroll
            for (int ni = 0; ni < 4; ++ni)
                #pragma unroll
                for (int j = 0; j < 4; ++j) {
                    int m = wr * 64 + mi * 16 + fk * 4 + j;
                    int n = wc * 64 + ni * 16 + fr;
                    C[(long)m * N + n] = f2bf(acc[mi][ni][j] * scale);
                }
    }
}

// ---------------------------------------------------------------------------
// Fallback Z-GEMM (small-ws path): C = A(bf16) @ B(f32,[K][N])
// ---------------------------------------------------------------------------
__global__ __launch_bounds__(256)
void gemm_kn(const unsigned short* __restrict__ Ap, const float* __restrict__ Bp,
             float* __restrict__ Cp, int M, int N, int K,
             long sA, long sB, long sC)
{
    __shared__ __align__(16) unsigned short lA[128 * 40];
    __shared__ __align__(16) unsigned short lB[64 * 40];

    const int bx = xcdswz(blockIdx.x, gridDim.x);
    const int mt = M >> 7;
    const int tm = bx % mt;
    const int tn = bx / mt;
    const int b  = blockIdx.y;
    const int tid = threadIdx.x;
    const int lane = tid & 63, wv = tid >> 6;
    const int wr = wv >> 1, wc = wv & 1;
    const int fr = lane & 15, fk = lane >> 4;

    f32x4 acc[4][2] = {};

    const unsigned short* A0 = Ap + (long)b * sA + (long)tm * 128 * K;
    const int nn    = tid & 63;
    const int khalf = tid >> 6;

    for (int k0 = 0; k0 < K; k0 += 32) {
        #pragma unroll
        for (int it = 0; it < 2; ++it) {
            int chunk = it * 256 + tid;
            int row = chunk >> 2;
            int kc  = (chunk & 3) << 3;
            *(uint4*)(&lA[lidx(row, kc)]) = *(const uint4*)(A0 + (long)row * K + k0 + kc);
        }
        {
            const float* Bb = Bp + (long)b * sB + (long)(k0 + khalf * 8) * N + (long)tn * 64 + nn;
            unsigned short t8[8];
            #pragma unroll
            for (int kk = 0; kk < 8; ++kk)
                t8[kk] = f2bf(Bb[(long)kk * N]);
            *(uint4*)(&lB[lidx(nn, khalf * 8)]) = *(uint4*)(&t8[0]);
        }
        __syncthreads();
        bf16x8 af[4], bfr[2];
        #pragma unroll
        for (int i = 0; i < 4; ++i)
            af[i] = *(const bf16x8*)(&lA[lidx(wr * 64 + i * 16 + fr, fk * 8)]);
        #pragma unroll
        for (int i = 0; i < 2; ++i)
            bfr[i] = *(const bf16x8*)(&lB[lidx(wc * 32 + i * 16 + fr, fk * 8)]);
        #pragma unroll
        for (int mi = 0; mi < 4; ++mi)
            #pragma unroll
            for (int ni = 0; ni < 2; ++ni)
                acc[mi][ni] = __builtin_amdgcn_mfma_f32_16x16x32_bf16(af[mi], bfr[ni], acc[mi][ni], 0, 0, 0);
        __syncthreads();
    }

    float* C = Cp + (long)b * sC + ((long)tm * 128) * N + (long)tn * 64;
    #pragma unroll
    for (int mi = 0; mi < 4; ++mi)
        #pragma unroll
        for (int ni = 0; ni < 2; ++ni)
            #pragma unroll
            for (int j = 0; j < 4; ++j) {
                int m = wr * 64 + mi * 16 + fk * 4 + j;
                int n = wc * 32 + ni * 16 + fr;
                C[(long)m * N + n] = acc[mi][ni][j];
            }
}

// ---------------------------------------------------------------------------
// Row softmax in place on S (bf16), rows of length 4096.
// ---------------------------------------------------------------------------
__global__ __launch_bounds__(256)
void softmax_rows(unsigned short* __restrict__ S, const unsigned char* __restrict__ mask)
{
    const int row = blockIdx.x;
    const int b = row >> 9;
    const long base = (long)row * 4096;
    const int tid = threadIdx.x, lane = tid & 63, wv = tid >> 6;
    __shared__ float red[8];

    uint4 s0 = *(const uint4*)(S + base + tid * 16);
    uint4 s1 = *(const uint4*)(S + base + tid * 16 + 8);
    uint4 mv = *(const uint4*)(mask + (long)b * 4096 + tid * 16);
    const unsigned char* mb = (const unsigned char*)&mv;

    unsigned int words[8] = { s0.x, s0.y, s0.z, s0.w, s1.x, s1.y, s1.z, s1.w };
    float x[16];
    #pragma unroll
    for (int i = 0; i < 8; ++i) {
        x[2 * i]     = bf2f((unsigned short)(words[i] & 0xffffu));
        x[2 * i + 1] = bf2f((unsigned short)(words[i] >> 16));
    }
    #pragma unroll
    for (int i = 0; i < 16; ++i)
        if (mb[i]) x[i] = -1e30f;

    float m = x[0];
    #pragma unroll
    for (int i = 1; i < 16; ++i) m = fmaxf(m, x[i]);
    #pragma unroll
    for (int off = 32; off; off >>= 1) m = fmaxf(m, __shfl_xor(m, off));
    if (lane == 0) red[wv] = m;
    __syncthreads();
    m = fmaxf(fmaxf(red[0], red[1]), fmaxf(red[2], red[3]));

    float p[16];
    float s = 0.f;
    #pragma unroll
    for (int i = 0; i < 16; ++i) { p[i] = __expf(x[i] - m); s += p[i]; }
    #pragma unroll
    for (int off = 32; off; off >>= 1) s += __shfl_xor(s, off);
    if (lane == 0) red[4 + wv] = s;
    __syncthreads();
    s = (red[4] + red[5]) + (red[6] + red[7]);
    const float inv = 1.0f / s;

    unsigned int ow[8];
    #pragma unroll
    for (int i = 0; i < 8; ++i) {
        unsigned int lo = f2bf(p[2 * i] * inv);
        unsigned int hi = f2bf(p[2 * i + 1] * inv);
        ow[i] = lo | (hi << 16);
    }
    uint4 o0 = { ow[0], ow[1], ow[2], ow[3] };
    uint4 o1 = { ow[4], ow[5], ow[6], ow[7] };
    *(uint4*)(S + base + tid * 16)     = o0;
    *(uint4*)(S + base + tid * 16 + 8) = o1;
}

// ---------------------------------------------------------------------------
extern "C" void kernel_launch(void* const* d_in, const int* in_sizes, int n_in,
                              void* d_out, int out_size, void* d_ws, size_t ws_size,
                              hipStream_t stream)
{
    const float*         H    = (const float*)d_in[0];
    const float*         G    = (const float*)d_in[1];
    const unsigned char* mask = (const unsigned char*)d_in[2];
    const float*         Wk   = (const float*)d_in[3];
    const float*         Wq   = (const float*)d_in[4];
    float*               out  = (float*)d_out;

    const long nK = (long)8 * 4096 * 256;
    const long nQ = (long)8 * 512 * 256;
    const long nS = (long)8 * 512 * 4096;
    const long nH = (long)8 * 1280 * 4096;

    unsigned short* Kb  = (unsigned short*)d_ws;
    unsigned short* Qb  = Kb + nK;
    unsigned short* Sb  = Qb + nQ;
    unsigned short* Hbt = Sb + nS;
    const bool big = ws_size >= (size_t)(nK + nQ + nS + nH) * 2;

    if (big) {
        // 1) K = H @ Wk^T (M=32768,N=256,K=1280) + fused H->Hbt transpose
        gemm_proj<true><<<dim3(512, 1), 256, 0, stream>>>(
            H, Wk, Kb, 32768, 256, 1280, Hbt);
        // 2) Q = G @ Wq^T (M=4096,N=256,K=768)
        gemm_proj<false><<<dim3(64, 1), 256, 0, stream>>>(
            G, Wq, Qb, 4096, 256, 768, nullptr);
        // 3) S = Q @ K^T * scale  per batch (M=512,N=4096,K=256)
        gemm_bt16s<false><<<dim3(128, 8), 256, 0, stream>>>(
            Qb, Kb, Sb, 512, 4096, 256,
            (long)512 * 256, (long)4096 * 256, (long)512 * 4096, 0.0625f);
        // 4) softmax
        softmax_rows<<<dim3(4096), 256, 0, stream>>>(Sb, mask);
        // 5) Z = alpha @ Hbt^T  per batch (M=512,N=1280,K=4096), f32 out
        gemm_bt16s<true><<<dim3(40, 8), 256, 0, stream>>>(
            Sb, Hbt, out, 512, 1280, 4096,
            (long)512 * 4096, (long)1280 * 4096, (long)512 * 1280, 1.0f);
    } else {
        gemm_proj<false><<<dim3(512, 1), 256, 0, stream>>>(
            H, Wk, Kb, 32768, 256, 1280, nullptr);
        gemm_proj<false><<<dim3(64, 1), 256, 0, stream>>>(
            G, Wq, Qb, 4096, 256, 768, nullptr);
        gemm_bt16s<false><<<dim3(128, 8), 256, 0, stream>>>(
            Qb, Kb, Sb, 512, 4096, 256,
            (long)512 * 256, (long)4096 * 256, (long)512 * 4096, 0.0625f);
        softmax_rows<<<dim3(4096), 256, 0, stream>>>(Sb, mask);
        gemm_kn<<<dim3(80, 8), 256, 0, stream>>>(
            Sb, H, out, 512, 1280, 4096,
            (long)512 * 4096, (long)4096 * 1280, (long)512 * 1280);
    }
}

// Round 7
// 271.709 us; speedup vs baseline: 1.2151x; 1.0390x over previous
//
#include <hip/hip_runtime.h>
#include <hip/hip_bf16.h>
#include <stdint.h>

// B=8, L=4096, T=512, D_H=1280, D_G=768, D_P=256, scale = 1/16

typedef float f32x4 __attribute__((ext_vector_type(4)));
typedef short bf16x8 __attribute__((ext_vector_type(8)));

__device__ __forceinline__ unsigned short f2bf(float f) {
    __hip_bfloat16 h = __float2bfloat16(f);
    return __builtin_bit_cast(unsigned short, h);
}
__device__ __forceinline__ float bf2f(unsigned short h) {
    union { uint32_t u; float f; } v; v.u = ((uint32_t)h) << 16;
    return v.f;
}

// bijective XCD-chunk swizzle (gridDim.x % 8 == 0 at all call sites)
__device__ __forceinline__ int xcdswz(int bx, int nbx) {
    int cpx = nbx >> 3;
    return (bx & 7) * cpx + (bx >> 3);
}

// async global->LDS, 16B per lane; LDS dest = wave-uniform base + lane*16
__device__ __forceinline__ void gload16(const unsigned short* g, unsigned short* l) {
    __builtin_amdgcn_global_load_lds(
        (const __attribute__((address_space(1))) void*)g,
        (__attribute__((address_space(3))) void*)l,
        16, 0, 0);
}

// LDS index for f32-staged kernels (padded stride 40 + granule XOR swizzle)
__device__ __forceinline__ int lidx(int row, int kshort) {
    return row * 40 + (((kshort >> 3) ^ ((row >> 3) & 3)) << 3) + (kshort & 7);
}

// ---------------------------------------------------------------------------
// f32 -> bf16 contiguous convert (for Wk); n4 = count/4
// ---------------------------------------------------------------------------
__global__ __launch_bounds__(256)
void cvt_f32_bf16(const float* __restrict__ in, unsigned short* __restrict__ out, long n4)
{
    long i = (long)blockIdx.x * 256 + threadIdx.x;
    if (i >= n4) return;
    float4 v = ((const float4*)in)[i];
    ushort4 w;
    w.x = f2bf(v.x); w.y = f2bf(v.y); w.z = f2bf(v.z); w.w = f2bf(v.w);
    ((ushort4*)out)[i] = w;
}

// ---------------------------------------------------------------------------
// H [8][4096][1280] f32 -> Hbt [8][1280][4096] bf16 (transposed)
//                       -> Hb  [8][4096][1280] bf16 (row-major, coalesced)
// 64x64 tiles via LDS; 16-short-granule XOR swizzle breaks bank conflicts.
// ---------------------------------------------------------------------------
template<bool WRITE_HB>
__global__ __launch_bounds__(256)
void cvt_h(const float* __restrict__ H, unsigned short* __restrict__ Hbt,
           unsigned short* __restrict__ Hb)
{
    __shared__ unsigned short lT[64 * 72];
    const int ntile = 64 * 20 * 8;
    for (int tileid = blockIdx.x; tileid < ntile; tileid += gridDim.x) {
        int tmp = tileid;
        const int dt = tmp % 20; tmp /= 20;
        const int lt = tmp % 64;
        const int b  = tmp / 64;
        const int l0 = lt * 64, d0 = dt * 64;
        const float* Hs = H + ((long)b * 4096 + l0) * 1280 + d0;
        #pragma unroll
        for (int it = 0; it < 4; ++it) {
            int chunk = it * 256 + threadIdx.x;
            int lr = chunk >> 4, dc4 = (chunk & 15) << 2;
            float4 v = *(const float4*)(Hs + (long)lr * 1280 + dc4);
            unsigned short w[4] = { f2bf(v.x), f2bf(v.y), f2bf(v.z), f2bf(v.w) };
            if constexpr (WRITE_HB) {
                ushort4 wb = { w[0], w[1], w[2], w[3] };
                *(ushort4*)(Hb + ((long)b * 4096 + l0 + lr) * 1280 + d0 + dc4) = wb;
            }
            #pragma unroll
            for (int j = 0; j < 4; ++j) {
                int d = dc4 + j;
                int sl = (lr & 15) | ((((lr >> 4) ^ (d >> 2)) & 3) << 4);
                lT[d * 72 + sl] = w[j];
            }
        }
        __syncthreads();
        {
            int drow = threadIdx.x >> 2, lc = threadIdx.x & 3;
            int slc = lc ^ ((drow >> 2) & 3);
            const uint4* src = (const uint4*)(lT + drow * 72 + slc * 16);
            unsigned short* dst = Hbt + ((long)b * 1280 + d0 + drow) * 4096 + l0 + lc * 16;
            uint4 v0 = src[0], v1 = src[1];
            *(uint4*)(dst)     = v0;
            *(uint4*)(dst + 8) = v1;
        }
        __syncthreads();
    }
}

// ---------------------------------------------------------------------------
// Projection GEMM: C[m,n] = sum_k A[m,k]*B[n,k], f32 inputs (cvt in staging),
// bf16 out. Tile 128x128, BK=32, 4 waves 2x2. tn-fastest mapping.
// ---------------------------------------------------------------------------
__global__ __launch_bounds__(256)
void gemm_proj(const float* __restrict__ Ap, const float* __restrict__ Bp,
               unsigned short* __restrict__ Cp, int M, int N, int K)
{
    __shared__ __align__(16) unsigned short lA[128 * 40];
    __shared__ __align__(16) unsigned short lB[128 * 40];

    const int bx = xcdswz(blockIdx.x, gridDim.x);
    const int nt = N >> 7;
    const int tm = bx / nt;
    const int tn = bx % nt;
    const int tid = threadIdx.x;
    const int lane = tid & 63, wv = tid >> 6;
    const int wr = wv >> 1, wc = wv & 1;
    const int fr = lane & 15, fk = lane >> 4;

    f32x4 acc[4][4] = {};

    for (int k0 = 0; k0 < K; k0 += 32) {
        {
            const float* A = Ap + (long)tm * 128 * K + k0;
            #pragma unroll
            for (int it = 0; it < 4; ++it) {
                int chunk = it * 256 + tid;
                int row = chunk >> 3;
                int kc  = (chunk & 7) << 2;
                const float4 v = *(const float4*)(A + (long)row * K + kc);
                ushort4 w;
                w.x = f2bf(v.x); w.y = f2bf(v.y); w.z = f2bf(v.z); w.w = f2bf(v.w);
                *(ushort4*)(&lA[lidx(row, kc)]) = w;
            }
        }
        {
            const float* B = Bp + (long)tn * 128 * K + k0;
            #pragma unroll
            for (int it = 0; it < 4; ++it) {
                int chunk = it * 256 + tid;
                int row = chunk >> 3;
                int kc  = (chunk & 7) << 2;
                const float4 v = *(const float4*)(B + (long)row * K + kc);
                ushort4 w;
                w.x = f2bf(v.x); w.y = f2bf(v.y); w.z = f2bf(v.z); w.w = f2bf(v.w);
                *(ushort4*)(&lB[lidx(row, kc)]) = w;
            }
        }
        __syncthreads();
        bf16x8 af[4], bfr[4];
        #pragma unroll
        for (int i = 0; i < 4; ++i)
            af[i] = *(const bf16x8*)(&lA[lidx(wr * 64 + i * 16 + fr, fk * 8)]);
        #pragma unroll
        for (int i = 0; i < 4; ++i)
            bfr[i] = *(const bf16x8*)(&lB[lidx(wc * 64 + i * 16 + fr, fk * 8)]);
        #pragma unroll
        for (int mi = 0; mi < 4; ++mi)
            #pragma unroll
            for (int ni = 0; ni < 4; ++ni)
                acc[mi][ni] = __builtin_amdgcn_mfma_f32_16x16x32_bf16(af[mi], bfr[ni], acc[mi][ni], 0, 0, 0);
        __syncthreads();
    }

    unsigned short* C = Cp + ((long)tm * 128) * N + (long)tn * 128;
    #pragma unroll
    for (int mi = 0; mi < 4; ++mi)
        #pragma unroll
        for (int ni = 0; ni < 4; ++ni)
            #pragma unroll
            for (int j = 0; j < 4; ++j) {
                int m = wr * 64 + mi * 16 + fk * 4 + j;
                int n = wc * 64 + ni * 16 + fr;
                C[(long)m * N + n] = f2bf(acc[mi][ni][j]);
            }
}

// ---------------------------------------------------------------------------
// All-bf16 C = scale*A@B^T (m97 structure). Tile 128x128, BK=64, 4 waves 2x2
// (wave 64x64). gload16 staging, pre-swizzled source + XOR-swizzled reads.
// OF32: f32 output (for Z), else bf16.
// ---------------------------------------------------------------------------
template<bool OF32>
__global__ __launch_bounds__(256)
void gemm_bt16s(const unsigned short* __restrict__ Ap, const unsigned short* __restrict__ Bp,
                void* __restrict__ Cp, int M, int N, int K,
                long sA, long sB, long sC, float scale)
{
    __shared__ __align__(16) unsigned short lA[128 * 64];   // 16KB
    __shared__ __align__(16) unsigned short lB[128 * 64];   // 16KB

    const int bx = xcdswz(blockIdx.x, gridDim.x);
    const int nt = N >> 7;
    const int tm = bx / nt, tn = bx % nt;   // tn fastest (A-strip sharers adjacent)
    const int b  = blockIdx.y;
    const int tid = threadIdx.x;
    const int lane = tid & 63, wv = tid >> 6;
    const int wr = wv >> 1, wc = wv & 1;
    const int fr = lane & 15, fk = lane >> 4;

    f32x4 acc[4][4] = {};

    const unsigned short* A0 = Ap + (long)b * sA + (long)tm * 128 * K;
    const unsigned short* B0 = Bp + (long)b * sB + (long)tn * 128 * K;

    for (int k0 = 0; k0 < K; k0 += 64) {
        // 128 rows x 8 chunks(16B) = 1024 slots per tile; 4 issues/thread each
        #pragma unroll
        for (int q = 0; q < 4; ++q) {
            int slot = wv * 256 + q * 64 + lane;
            int row = slot >> 3, c = slot & 7;
            int ks = (c ^ (row & 7)) << 3;                 // pre-swizzled source chunk
            gload16(A0 + (long)row * K + k0 + ks, lA + (size_t)(wv * 256 + q * 64) * 8);
            gload16(B0 + (long)row * K + k0 + ks, lB + (size_t)(wv * 256 + q * 64) * 8);
        }
        __syncthreads();
        bf16x8 af[2][4], bfv[2][4];
        #pragma unroll
        for (int ks = 0; ks < 2; ++ks) {
            int csw = ((ks * 4 + fk) ^ (fr & 7)) << 3;
            #pragma unroll
            for (int i = 0; i < 4; ++i) {
                af[ks][i]  = *(const bf16x8*)(lA + (wr * 64 + i * 16 + fr) * 64 + csw);
                bfv[ks][i] = *(const bf16x8*)(lB + (wc * 64 + i * 16 + fr) * 64 + csw);
            }
        }
        #pragma unroll
        for (int mi = 0; mi < 4; ++mi)
            #pragma unroll
            for (int ni = 0; ni < 4; ++ni)
                #pragma unroll
                for (int ks = 0; ks < 2; ++ks)
                    acc[mi][ni] = __builtin_amdgcn_mfma_f32_16x16x32_bf16(af[ks][mi], bfv[ks][ni], acc[mi][ni], 0, 0, 0);
        __syncthreads();
    }

    if constexpr (OF32) {
        float* C = (float*)Cp + (long)b * sC + ((long)tm * 128) * N + (long)tn * 128;
        #pragma unroll
        for (int mi = 0; mi < 4; ++mi)
            #pragma unroll
            for (int ni = 0; ni < 4; ++ni)
                #pragma unroll
                for (int j = 0; j < 4; ++j) {
                    int m = wr * 64 + mi * 16 + fk * 4 + j;
                    int n = wc * 64 + ni * 16 + fr;
                    C[(long)m * N + n] = acc[mi][ni][j] * scale;
                }
    } else {
        unsigned short* C = (unsigned short*)Cp + (long)b * sC + ((long)tm * 128) * N + (long)tn * 128;
        #pragma unroll
        for (int mi = 0; mi < 4; ++mi)
            #pragma unroll
            for (int ni = 0; ni < 4; ++ni)
                #pragma unroll
                for (int j = 0; j < 4; ++j) {
                    int m = wr * 64 + mi * 16 + fk * 4 + j;
                    int n = wc * 64 + ni * 16 + fr;
                    C[(long)m * N + n] = f2bf(acc[mi][ni][j] * scale);
                }
    }
}

// ---------------------------------------------------------------------------
// Fallback Z-GEMM (small-ws path): C = A(bf16) @ B(f32,[K][N])
// ---------------------------------------------------------------------------
__global__ __launch_bounds__(256)
void gemm_kn(const unsigned short* __restrict__ Ap, const float* __restrict__ Bp,
             float* __restrict__ Cp, int M, int N, int K,
             long sA, long sB, long sC)
{
    __shared__ __align__(16) unsigned short lA[128 * 40];
    __shared__ __align__(16) unsigned short lB[64 * 40];

    const int bx = xcdswz(blockIdx.x, gridDim.x);
    const int mt = M >> 7;
    const int tm = bx % mt;
    const int tn = bx / mt;
    const int b  = blockIdx.y;
    const int tid = threadIdx.x;
    const int lane = tid & 63, wv = tid >> 6;
    const int wr = wv >> 1, wc = wv & 1;
    const int fr = lane & 15, fk = lane >> 4;

    f32x4 acc[4][2] = {};

    const unsigned short* A0 = Ap + (long)b * sA + (long)tm * 128 * K;
    const int nn    = tid & 63;
    const int khalf = tid >> 6;

    for (int k0 = 0; k0 < K; k0 += 32) {
        #pragma unroll
        for (int it = 0; it < 2; ++it) {
            int chunk = it * 256 + tid;
            int row = chunk >> 2;
            int kc  = (chunk & 3) << 3;
            *(uint4*)(&lA[lidx(row, kc)]) = *(const uint4*)(A0 + (long)row * K + k0 + kc);
        }
        {
            const float* Bb = Bp + (long)b * sB + (long)(k0 + khalf * 8) * N + (long)tn * 64 + nn;
            unsigned short t8[8];
            #pragma unroll
            for (int kk = 0; kk < 8; ++kk)
                t8[kk] = f2bf(Bb[(long)kk * N]);
            *(uint4*)(&lB[lidx(nn, khalf * 8)]) = *(uint4*)(&t8[0]);
        }
        __syncthreads();
        bf16x8 af[4], bfr[2];
        #pragma unroll
        for (int i = 0; i < 4; ++i)
            af[i] = *(const bf16x8*)(&lA[lidx(wr * 64 + i * 16 + fr, fk * 8)]);
        #pragma unroll
        for (int i = 0; i < 2; ++i)
            bfr[i] = *(const bf16x8*)(&lB[lidx(wc * 32 + i * 16 + fr, fk * 8)]);
        #pragma unroll
        for (int mi = 0; mi < 4; ++mi)
            #pragma unroll
            for (int ni = 0; ni < 2; ++ni)
                acc[mi][ni] = __builtin_amdgcn_mfma_f32_16x16x32_bf16(af[mi], bfr[ni], acc[mi][ni], 0, 0, 0);
        __syncthreads();
    }

    float* C = Cp + (long)b * sC + ((long)tm * 128) * N + (long)tn * 64;
    #pragma unroll
    for (int mi = 0; mi < 4; ++mi)
        #pragma unroll
        for (int ni = 0; ni < 2; ++ni)
            #pragma unroll
            for (int j = 0; j < 4; ++j) {
                int m = wr * 64 + mi * 16 + fk * 4 + j;
                int n = wc * 32 + ni * 16 + fr;
                C[(long)m * N + n] = acc[mi][ni][j];
            }
}

// ---------------------------------------------------------------------------
// Row softmax in place on S (bf16), rows of length 4096.
// ---------------------------------------------------------------------------
__global__ __launch_bounds__(256)
void softmax_rows(unsigned short* __restrict__ S, const unsigned char* __restrict__ mask)
{
    const int row = blockIdx.x;
    const int b = row >> 9;
    const long base = (long)row * 4096;
    const int tid = threadIdx.x, lane = tid & 63, wv = tid >> 6;
    __shared__ float red[8];

    uint4 s0 = *(const uint4*)(S + base + tid * 16);
    uint4 s1 = *(const uint4*)(S + base + tid * 16 + 8);
    uint4 mv = *(const uint4*)(mask + (long)b * 4096 + tid * 16);
    const unsigned char* mb = (const unsigned char*)&mv;

    unsigned int words[8] = { s0.x, s0.y, s0.z, s0.w, s1.x, s1.y, s1.z, s1.w };
    float x[16];
    #pragma unroll
    for (int i = 0; i < 8; ++i) {
        x[2 * i]     = bf2f((unsigned short)(words[i] & 0xffffu));
        x[2 * i + 1] = bf2f((unsigned short)(words[i] >> 16));
    }
    #pragma unroll
    for (int i = 0; i < 16; ++i)
        if (mb[i]) x[i] = -1e30f;

    float m = x[0];
    #pragma unroll
    for (int i = 1; i < 16; ++i) m = fmaxf(m, x[i]);
    #pragma unroll
    for (int off = 32; off; off >>= 1) m = fmaxf(m, __shfl_xor(m, off));
    if (lane == 0) red[wv] = m;
    __syncthreads();
    m = fmaxf(fmaxf(red[0], red[1]), fmaxf(red[2], red[3]));

    float p[16];
    float s = 0.f;
    #pragma unroll
    for (int i = 0; i < 16; ++i) { p[i] = __expf(x[i] - m); s += p[i]; }
    #pragma unroll
    for (int off = 32; off; off >>= 1) s += __shfl_xor(s, off);
    if (lane == 0) red[4 + wv] = s;
    __syncthreads();
    s = (red[4] + red[5]) + (red[6] + red[7]);
    const float inv = 1.0f / s;

    unsigned int ow[8];
    #pragma unroll
    for (int i = 0; i < 8; ++i) {
        unsigned int lo = f2bf(p[2 * i] * inv);
        unsigned int hi = f2bf(p[2 * i + 1] * inv);
        ow[i] = lo | (hi << 16);
    }
    uint4 o0 = { ow[0], ow[1], ow[2], ow[3] };
    uint4 o1 = { ow[4], ow[5], ow[6], ow[7] };
    *(uint4*)(S + base + tid * 16)     = o0;
    *(uint4*)(S + base + tid * 16 + 8) = o1;
}

// ---------------------------------------------------------------------------
extern "C" void kernel_launch(void* const* d_in, const int* in_sizes, int n_in,
                              void* d_out, int out_size, void* d_ws, size_t ws_size,
                              hipStream_t stream)
{
    const float*         H    = (const float*)d_in[0];
    const float*         G    = (const float*)d_in[1];
    const unsigned char* mask = (const unsigned char*)d_in[2];
    const float*         Wk   = (const float*)d_in[3];
    const float*         Wq   = (const float*)d_in[4];
    float*               out  = (float*)d_out;

    const long nK = (long)8 * 4096 * 256;     // Kb
    const long nQ = (long)8 * 512 * 256;      // Qb
    const long nS = (long)8 * 512 * 4096;     // Sb
    const long nH = (long)8 * 1280 * 4096;    // Hbt / Hb each
    const long nW = (long)256 * 1280;         // Wkb

    unsigned short* Kb  = (unsigned short*)d_ws;
    unsigned short* Qb  = Kb + nK;
    unsigned short* Sb  = Qb + nQ;
    unsigned short* Hbt = Sb + nS;
    unsigned short* Hb  = Hbt + nH;
    unsigned short* Wkb = Hb + nH;

    const size_t need2 = (size_t)(nK + nQ + nS + nH + nH + nW) * 2;  // ~221 MB
    const size_t need1 = (size_t)(nK + nQ + nS + nH) * 2;            // ~137 MB

    if (ws_size >= need2) {
        // 1) Wkb = bf16(Wk)
        cvt_f32_bf16<<<dim3(320), 256, 0, stream>>>(Wk, Wkb, nW / 4);
        // 2) Hb (row-major bf16) + Hbt (transposed bf16) from H, single pass
        cvt_h<true><<<dim3(2048), 256, 0, stream>>>(H, Hbt, Hb);
        // 3) K = Hb @ Wkb^T  (M=32768,N=256,K=1280) on the bf16 template
        gemm_bt16s<false><<<dim3(512, 1), 256, 0, stream>>>(
            Hb, Wkb, Kb, 32768, 256, 1280, 0, 0, 0, 1.0f);
        // 4) Q = G @ Wq^T (M=4096,N=256,K=768), f32-staged (small)
        gemm_proj<<<dim3(64, 1), 256, 0, stream>>>(G, Wq, Qb, 4096, 256, 768);
        // 5) S = Q @ K^T * scale  per batch (M=512,N=4096,K=256)
        gemm_bt16s<false><<<dim3(128, 8), 256, 0, stream>>>(
            Qb, Kb, Sb, 512, 4096, 256,
            (long)512 * 256, (long)4096 * 256, (long)512 * 4096, 0.0625f);
        // 6) softmax
        softmax_rows<<<dim3(4096), 256, 0, stream>>>(Sb, mask);
        // 7) Z = alpha @ Hbt^T  per batch (M=512,N=1280,K=4096), f32 out
        gemm_bt16s<true><<<dim3(40, 8), 256, 0, stream>>>(
            Sb, Hbt, out, 512, 1280, 4096,
            (long)512 * 4096, (long)1280 * 4096, (long)512 * 1280, 1.0f);
    } else if (ws_size >= need1) {
        gemm_proj<<<dim3(512, 1), 256, 0, stream>>>(H, Wk, Kb, 32768, 256, 1280);
        gemm_proj<<<dim3(64, 1), 256, 0, stream>>>(G, Wq, Qb, 4096, 256, 768);
        cvt_h<false><<<dim3(2048), 256, 0, stream>>>(H, Hbt, nullptr);
        gemm_bt16s<false><<<dim3(128, 8), 256, 0, stream>>>(
            Qb, Kb, Sb, 512, 4096, 256,
            (long)512 * 256, (long)4096 * 256, (long)512 * 4096, 0.0625f);
        softmax_rows<<<dim3(4096), 256, 0, stream>>>(Sb, mask);
        gemm_bt16s<true><<<dim3(40, 8), 256, 0, stream>>>(
            Sb, Hbt, out, 512, 1280, 4096,
            (long)512 * 4096, (long)1280 * 4096, (long)512 * 1280, 1.0f);
    } else {
        gemm_proj<<<dim3(512, 1), 256, 0, stream>>>(H, Wk, Kb, 32768, 256, 1280);
        gemm_proj<<<dim3(64, 1), 256, 0, stream>>>(G, Wq, Qb, 4096, 256, 768);
        gemm_bt16s<false><<<dim3(128, 8), 256, 0, stream>>>(
            Qb, Kb, Sb, 512, 4096, 256,
            (long)512 * 256, (long)4096 * 256, (long)512 * 4096, 0.0625f);
        softmax_rows<<<dim3(4096), 256, 0, stream>>>(Sb, mask);
        gemm_kn<<<dim3(80, 8), 256, 0, stream>>>(
            Sb, H, out, 512, 1280, 4096,
            (long)512 * 4096, (long)4096 * 1280, (long)512 * 1280);
    }
}